// Round 1
// baseline (679.162 us; speedup 1.0000x reference)
//
#include <hip/hip_runtime.h>

// ---------- types ----------
typedef __attribute__((ext_vector_type(8))) short bf16x8;
typedef __attribute__((ext_vector_type(4))) float f32x4;

static __device__ __forceinline__ unsigned short f2bf(float x) {
    unsigned int u = __float_as_uint(x);
    u += 0x7fffu + ((u >> 16) & 1u);   // RTNE, finite inputs
    return (unsigned short)(u >> 16);
}

// Workgroup barrier WITHOUT vmcnt drain: LDS ordering only.
static __device__ __forceinline__ void barrier_lds_only() {
    __asm__ volatile("s_waitcnt lgkmcnt(0)\n\ts_barrier" ::: "memory");
}

// ---------- K0: four fp32->bf16 transposes in one launch ----------
__global__ void transpose4(const float* __restrict__ s0, const float* __restrict__ s1,
                           const float* __restrict__ s2, const float* __restrict__ s3,
                           unsigned short* __restrict__ d0, unsigned short* __restrict__ d1,
                           unsigned short* __restrict__ d2, unsigned short* __restrict__ d3) {
    int which = blockIdx.y;
    const float* src = which == 0 ? s0 : which == 1 ? s1 : which == 2 ? s2 : s3;
    unsigned short* dst = which == 0 ? d0 : which == 1 ? d1 : which == 2 ? d2 : d3;
    int K = (which == 0) ? 512 : 256;
    int idx = blockIdx.x * 256 + threadIdx.x;
    if (idx >= K * 256) return;
    int k = idx >> 8;          // N = 256
    int n = idx & 255;
    dst[n * K + k] = f2bf(src[idx]);
}

// ---------- GEMM: C[M,N] = A[M,K] @ Bt[N,K]^T + bias, bf16 MFMA ----------
template<bool GATHER>
__global__ __launch_bounds__(256, 4) void gemm_mfma(
    const void* __restrict__ Aptr, const int* __restrict__ tokens,
    const unsigned short* __restrict__ Bt, const float* __restrict__ bias,
    float* __restrict__ C, int M, int N, int K)
{
    const int bn0 = blockIdx.x * 64;
    const int m0  = blockIdx.y * 64;
    const int tid = threadIdx.x;

    __shared__ unsigned short As[64 * 40];
    __shared__ unsigned short Bs[64 * 40];
    __shared__ int tok[64];

    if (GATHER) {
        if (tid < 64) tok[tid] = tokens[m0 + tid];
        __syncthreads();
    }

    const int r  = tid >> 2;
    const int c0 = (tid & 3) * 8;
    const int w  = tid >> 6;
    const int L  = tid & 63;
    const int ml = L & 15;
    const int q  = L >> 4;
    const int kq = q * 8;

    f32x4 acc[4] = {};

    for (int k0 = 0; k0 < K; k0 += 32) {
        unsigned short tmp[8];
        if (GATHER) {
            const float* src = (const float*)Aptr + (size_t)tok[r] * K + k0 + c0;
            float4 f0 = *(const float4*)(src);
            float4 f1 = *(const float4*)(src + 4);
            tmp[0]=f2bf(f0.x); tmp[1]=f2bf(f0.y); tmp[2]=f2bf(f0.z); tmp[3]=f2bf(f0.w);
            tmp[4]=f2bf(f1.x); tmp[5]=f2bf(f1.y); tmp[6]=f2bf(f1.z); tmp[7]=f2bf(f1.w);
        } else {
            const unsigned short* src = (const unsigned short*)Aptr + (size_t)(m0 + r) * K + k0 + c0;
            *(uint4*)tmp = *(const uint4*)src;
        }
        *(uint4*)&As[r * 40 + c0] = *(const uint4*)tmp;
        *(uint4*)&Bs[r * 40 + c0] = *(const uint4*)(Bt + (size_t)(bn0 + r) * K + k0 + c0);
        __syncthreads();

        bf16x8 av = *(const bf16x8*)&As[(16 * w + ml) * 40 + kq];
#pragma unroll
        for (int ns = 0; ns < 4; ++ns) {
            bf16x8 bv = *(const bf16x8*)&Bs[(ns * 16 + ml) * 40 + kq];
            acc[ns] = __builtin_amdgcn_mfma_f32_16x16x32_bf16(av, bv, acc[ns], 0, 0, 0);
        }
        __syncthreads();
    }

#pragma unroll
    for (int ns = 0; ns < 4; ++ns) {
        int gn = bn0 + ns * 16 + ml;
        float bv = bias[gn];
#pragma unroll
        for (int rr = 0; rr < 4; ++rr) {
            int gm = m0 + 16 * w + q * 4 + rr;
            C[(size_t)gm * N + gn] = acc[ns][rr] + bv;
        }
    }
}

// ---------- Fused pipelined scan: layer1 scan + (h1@W2) GEMV + layer2 scan ----------
// 12 waves per WG, one WG per batch row. Three roles, skewed pipeline:
//   role A (waves 0-3):  h1[t]   = tanh(xw1[t] + h1[t-1] @ U1)       t = tick
//   role B (waves 4-7):  p[t-1]  = h1[t-1] @ W2                      (K3 folded in)
//   role C (waves 8-11): h2[t-2] = tanh(p[t-2] + b2 + h2[t-3] @ U2)
// All buffers double-buffered in LDS; at tick T everything READS parity RP=(T-1)&1
// and WRITES parity RP^1. One lds-only barrier per tick; 514 ticks.
__global__ __launch_bounds__(768, 1) void rnn_fused(
    const float* __restrict__ xw,           // [64][512][256] f32 (= emb@W1+b1)
    const unsigned short* __restrict__ U1t, // [256][256] bf16, [n][k]
    const unsigned short* __restrict__ W2t, // [256][256] bf16, [n][k]
    const unsigned short* __restrict__ U2t, // [256][256] bf16, [n][k]
    const float* __restrict__ b2,           // [256]
    float* __restrict__ out_last)           // [64][256] f32
{
    const int b    = blockIdx.x;
    const int tid  = threadIdx.x;
    const int w    = tid >> 6;      // 0..11
    const int role = w >> 2;        // 0=A, 1=B, 2=C
    const int sw   = w & 3;         // sub-wave within role: which 64-col group
    const int L    = tid & 63;
    const int col  = sw * 64 + L;   // this thread's output column
    const int q    = L >> 4;
    const int ml   = L & 15;

    __shared__ unsigned short h1sh[2][256];
    __shared__ unsigned short h2sh[2][256];
    __shared__ float          psh[2][256];

    // B-operand fragments for this wave's role (loop-invariant, register-resident)
    const unsigned short* Bmat = (role == 0) ? U1t : (role == 1) ? W2t : U2t;
    bf16x8 ufrag[4][8];
#pragma unroll
    for (int i = 0; i < 4; ++i) {
        const unsigned short* up = Bmat + (size_t)((sw * 4 + i) * 16 + ml) * 256 + q * 8;
#pragma unroll
        for (int kt = 0; kt < 8; ++kt)
            ufrag[i][kt] = *(const bf16x8*)(up + kt * 32);
    }

    if (tid < 256) { h1sh[1][tid] = 0; h2sh[1][tid] = 0; }

    // role A: 4-deep xw prefetch pipeline; role C: bias
    float b2c = 0.f;
    const float* xb = xw + (size_t)b * 512 * 256 + col;
    const float* xpf = xb + 4 * 256;
    float xq0 = 0.f, xq1 = 0.f, xq2 = 0.f, xq3 = 0.f;
    if (role == 0) {
        xq0 = xb[0 * 256]; xq1 = xb[1 * 256]; xq2 = xb[2 * 256]; xq3 = xb[3 * 256];
    } else if (role == 2) {
        b2c = b2[col];
    }

    float lastv = 0.f;
    __syncthreads();

// A-broadcast matvec ladder: z = src_row(RP) @ ufrag, single 8-deep acc chain
#define LADDER(SRCBUF, RP)                                                           \
    bf16x8 af[8];                                                                    \
    _Pragma("unroll")                                                                \
    for (int kt = 0; kt < 8; ++kt)                                                   \
        af[kt] = *(const bf16x8*)&SRCBUF[RP][kt * 32 + q * 8];                       \
    f32x4 acc[4] = {};                                                               \
    _Pragma("unroll")                                                                \
    for (int kt = 0; kt < 8; ++kt) {                                                 \
        _Pragma("unroll")                                                            \
        for (int i = 0; i < 4; ++i)                                                  \
            acc[i] = __builtin_amdgcn_mfma_f32_16x16x32_bf16(af[kt], ufrag[i][kt], acc[i], 0, 0, 0); \
    }                                                                                \
    float z = (q == 0) ? acc[0][0] : (q == 1) ? acc[1][0] : (q == 2) ? acc[2][0] : acc[3][0];

#define TICK(RP, XQ, PF, DO_A, DO_B, DO_C)                                           \
    {                                                                                \
        if (DO_A && role == 0) {                                                     \
            float xnew = 0.f;                                                        \
            if (PF) { xnew = *xpf; xpf += 256; }                                     \
            LADDER(h1sh, RP)                                                         \
            z += XQ;                                                                 \
            float e  = __expf(2.f * z);          /* tanh(z) = 1 - 2/(e^{2z}+1) */    \
            float hn = 1.f - 2.f * __builtin_amdgcn_rcpf(e + 1.f);                   \
            h1sh[(RP) ^ 1][col] = f2bf(hn);                                          \
            XQ = xnew;                                                               \
        } else if (DO_B && role == 1) {                                              \
            LADDER(h1sh, RP)                                                         \
            psh[(RP) ^ 1][col] = z;                                                  \
        } else if (DO_C && role == 2) {                                              \
            float pv = psh[RP][col] + b2c;                                           \
            LADDER(h2sh, RP)                                                         \
            z += pv;                                                                 \
            float e  = __expf(2.f * z);                                              \
            float hn = 1.f - 2.f * __builtin_amdgcn_rcpf(e + 1.f);                   \
            lastv = hn;                                                              \
            h2sh[(RP) ^ 1][col] = f2bf(hn);                                          \
        }                                                                            \
        barrier_lds_only();                                                          \
    }

    // ticks 0..3: C idle for ticks 0,1 (its inputs don't exist yet)
    TICK(1, xq0, 1, 1, 1, 0)
    TICK(0, xq1, 1, 1, 1, 0)
    TICK(1, xq2, 1, 1, 1, 1)
    TICK(0, xq3, 1, 1, 1, 1)
    // ticks 4..507: steady state, all roles, prefetch on
    for (int tt = 4; tt < 508; tt += 4) {
        TICK(1, xq0, 1, 1, 1, 1)
        TICK(0, xq1, 1, 1, 1, 1)
        TICK(1, xq2, 1, 1, 1, 1)
        TICK(0, xq3, 1, 1, 1, 1)
    }
    // ticks 508..511: no prefetch (xq0..3 hold rows 508..511)
    TICK(1, xq0, 0, 1, 1, 1)
    TICK(0, xq1, 0, 1, 1, 1)
    TICK(1, xq2, 0, 1, 1, 1)
    TICK(0, xq3, 0, 1, 1, 1)
    // tick 512: B computes p[511], C computes h2[510]
    TICK(1, xq0, 0, 0, 1, 1)
    // tick 513: C computes h2[511]
    TICK(0, xq0, 0, 0, 0, 1)
#undef TICK
#undef LADDER

    if (role == 2) out_last[b * 256 + col] = lastv;   // h2[511], one thread per col
}

// ---------- head: softmax(h2 @ Wd + bd) ----------
__global__ void head_kernel(const float* __restrict__ h2, const float* __restrict__ Wd,
                            const float* __restrict__ bd, float* __restrict__ out)
{
    int tid = threadIdx.x;         // 128 threads: b = tid>>1, c = tid&1
    int b = tid >> 1, c = tid & 1;
    float s = bd[c];
    for (int jj = 0; jj < 256; ++jj) s = fmaf(h2[b * 256 + jj], Wd[jj * 2 + c], s);
    __shared__ float lg[128];
    lg[tid] = s;
    __syncthreads();
    float o0 = lg[b * 2 + 0], o1 = lg[b * 2 + 1];
    float m = fmaxf(o0, o1);
    float z = __expf(o0 - m) + __expf(o1 - m);
    out[tid] = __expf(s - m) * __builtin_amdgcn_rcpf(z);
}

// ---------- launch ----------
extern "C" void kernel_launch(void* const* d_in, const int* in_sizes, int n_in,
                              void* d_out, int out_size, void* d_ws, size_t ws_size,
                              hipStream_t stream) {
    const int*   tokens = (const int*)d_in[0];
    const float* emb    = (const float*)d_in[1];
    const float* W1     = (const float*)d_in[2];
    const float* U1     = (const float*)d_in[3];
    const float* b1     = (const float*)d_in[4];
    const float* W2     = (const float*)d_in[5];
    const float* U2     = (const float*)d_in[6];
    const float* b2     = (const float*)d_in[7];
    const float* Wd     = (const float*)d_in[8];
    const float* bd     = (const float*)d_in[9];
    float* out = (float*)d_out;

    char* ws = (char*)d_ws;
    float*          xw  = (float*)ws;                                  // 32 MB (xw1)
    char*           p   = ws + 33554432 + 16777216;                    // keep prior layout
    unsigned short* W1t = (unsigned short*)p;            p += 512 * 256 * 2;
    unsigned short* W2t = (unsigned short*)p;            p += 256 * 256 * 2;
    unsigned short* U1t = (unsigned short*)p;            p += 256 * 256 * 2;
    unsigned short* U2t = (unsigned short*)p;            p += 256 * 256 * 2;
    float*          h2  = (float*)p;

    const int M = 64 * 512;   // 32768

    // K0: weight/recurrence transposes to bf16 [N][K]
    transpose4<<<dim3(512, 4), 256, 0, stream>>>(W1, W2, U1, U2, W1t, W2t, U1t, U2t);

    // K1: xw1 = emb[tokens] @ W1 + b1   (gather fused)
    gemm_mfma<true><<<dim3(256 / 64, M / 64), 256, 0, stream>>>(
        emb, tokens, W1t, b1, xw, M, 256, 512);

    // K2: fused layer1-scan + W2-GEMV + layer2-scan -> h2 (f32 last state)
    rnn_fused<<<64, 768, 0, stream>>>(xw, U1t, W2t, U2t, b2, h2);

    // K3: softmax(h2 @ Wd + bd)
    head_kernel<<<1, 128, 0, stream>>>(h2, Wd, bd, out);
}